// Round 4
// baseline (610.677 us; speedup 1.0000x reference)
//
#include <hip/hip_runtime.h>

#define B_  2
#define NQ  2048
#define NK  2048
#define C_  256
#define H_  8
#define HD  32

typedef float f32x4 __attribute__((ext_vector_type(4)));
typedef __bf16 bf16x8 __attribute__((ext_vector_type(8)));
typedef unsigned short ushort8 __attribute__((ext_vector_type(8)));

// f32 -> bf16 round-to-nearest-even
static __device__ __forceinline__ unsigned short f2bf(float f) {
    unsigned int u = __builtin_bit_cast(unsigned int, f);
    u += 0x7FFFu + ((u >> 16) & 1u);
    return (unsigned short)(u >> 16);
}
static __device__ __forceinline__ float bf2f(unsigned short h) {
    unsigned int u = ((unsigned int)h) << 16;
    return __builtin_bit_cast(float, u);
}
// split f32 into bf16 hi (low 16 bits of result) + bf16 lo (high 16 bits);
// hi+lo approximates f to ~2^-19 relative.
static __device__ __forceinline__ unsigned int split1(float f) {
    unsigned short h = f2bf(f);
    unsigned short l = f2bf(f - bf2f(h));
    return (unsigned int)h | ((unsigned int)l << 16);
}
static __device__ __forceinline__ bf16x8 ld_bf16x8(const unsigned short* p) {
    return __builtin_bit_cast(bf16x8, *(const ushort8*)p);
}
// async global->LDS, 16B per lane; LDS dest = wave-uniform base + lane*16
static __device__ __forceinline__ void async16(const void* g, void* l) {
    __builtin_amdgcn_global_load_lds((__attribute__((address_space(1))) void*)g,
                                     (__attribute__((address_space(3))) void*)l,
                                     16, 0, 0);
}

// ---------------------------------------------------------------------------
// Projection GEMM, f32-accurate via split-bf16 4-term MFMA.
// out[m,j] = sum_k X[m,k]*W[k,j]; result stored as bf16 hi/lo pair.
// vmode==0: d*[((b*8+h)*2048 + row)*32 + dd]  (Q/K layout, j = h*32+dd)
// vmode==1: d*[((b*8+h)*32 + dd)*2048 + row]  (V transposed layout)
// grid (64,4), block 256 (4 waves); tile 64x64, K-step 32.
// ---------------------------------------------------------------------------
__global__ __launch_bounds__(256) void proj_kernel(const float* __restrict__ X,
                                                   const float* __restrict__ W,
                                                   unsigned short* __restrict__ dh,
                                                   unsigned short* __restrict__ dl,
                                                   int vmode)
{
    __shared__ unsigned short WtH[64][32];   // [col][k]  W^T hi
    __shared__ unsigned short WtL[64][32];   // [col][k]  W^T lo

    const int tid  = threadIdx.x;
    const int wave = tid >> 6;
    const int lane = tid & 63;
    const int n15  = lane & 15;
    const int quad = lane >> 4;
    const int m0   = blockIdx.x * 64;
    const int j0   = blockIdx.y * 64;

    f32x4 acc[4];
    acc[0] = 0.f; acc[1] = 0.f; acc[2] = 0.f; acc[3] = 0.f;

    const int sj  = tid >> 2;          // 0..63 staging col
    const int skc = (tid & 3) * 8;     // staging k-chunk
    const float* __restrict__ xrow = X + (size_t)(m0 + wave * 16 + n15) * C_;

    for (int k0 = 0; k0 < C_; k0 += 32) {
        ushort8 wh, wl;
        #pragma unroll
        for (int i = 0; i < 8; ++i) {
            unsigned int p = split1(W[(size_t)(k0 + skc + i) * C_ + j0 + sj]);
            wh[i] = (unsigned short)p;
            wl[i] = (unsigned short)(p >> 16);
        }
        *(ushort8*)&WtH[sj][skc] = wh;
        *(ushort8*)&WtL[sj][skc] = wl;
        __syncthreads();

        // A-frag: X[m=n15][k=quad*8+j], split f32 -> hi/lo
        f32x4 a0 = *(const f32x4*)(xrow + k0 + quad * 8);
        f32x4 a1 = *(const f32x4*)(xrow + k0 + quad * 8 + 4);
        ushort8 ah, al;
        #pragma unroll
        for (int i = 0; i < 4; ++i) {
            unsigned int p0 = split1(a0[i]);
            unsigned int p1 = split1(a1[i]);
            ah[i]     = (unsigned short)p0;  al[i]     = (unsigned short)(p0 >> 16);
            ah[i + 4] = (unsigned short)p1;  al[i + 4] = (unsigned short)(p1 >> 16);
        }
        bf16x8 Ah = __builtin_bit_cast(bf16x8, ah);
        bf16x8 Al = __builtin_bit_cast(bf16x8, al);

        #pragma unroll
        for (int f = 0; f < 4; ++f) {
            bf16x8 Bh = ld_bf16x8(&WtH[f * 16 + n15][quad * 8]);
            bf16x8 Bl = ld_bf16x8(&WtL[f * 16 + n15][quad * 8]);
            acc[f] = __builtin_amdgcn_mfma_f32_16x16x32_bf16(Al, Bl, acc[f], 0, 0, 0);
            acc[f] = __builtin_amdgcn_mfma_f32_16x16x32_bf16(Al, Bh, acc[f], 0, 0, 0);
            acc[f] = __builtin_amdgcn_mfma_f32_16x16x32_bf16(Ah, Bl, acc[f], 0, 0, 0);
            acc[f] = __builtin_amdgcn_mfma_f32_16x16x32_bf16(Ah, Bh, acc[f], 0, 0, 0);
        }
        __syncthreads();
    }

    // epilogue: C/D layout row = quad*4+r, col = n15; store split pair
    #pragma unroll
    for (int f = 0; f < 4; ++f) {
        const int j = j0 + f * 16 + n15;
        const int h = j >> 5, dd = j & 31;
        #pragma unroll
        for (int r = 0; r < 4; ++r) {
            const int grow = m0 + wave * 16 + quad * 4 + r;
            const int b = grow >> 11, row = grow & 2047;
            unsigned int p = split1(acc[f][r]);
            size_t idx;
            if (vmode) idx = (size_t)((b * H_ + h) * HD + dd) * NK + row;
            else       idx = (size_t)((b * H_ + h) * NK + row) * HD + dd;
            dh[idx] = (unsigned short)p;
            dl[idx] = (unsigned short)(p >> 16);
        }
    }
}

// ---------------------------------------------------------------------------
// Output projection: out[m,j] = sum_k x[m,k]*Wp[k,j] + bp[j], f32 out.
// x arrives pre-split (Xh/Xl bf16); Wp split during staging.
// ---------------------------------------------------------------------------
__global__ __launch_bounds__(256) void outproj_kernel(const unsigned short* __restrict__ Xh,
                                                      const unsigned short* __restrict__ Xl,
                                                      const float* __restrict__ W,
                                                      const float* __restrict__ bias,
                                                      float* __restrict__ out)
{
    __shared__ unsigned short WtH[64][32];
    __shared__ unsigned short WtL[64][32];

    const int tid  = threadIdx.x;
    const int wave = tid >> 6;
    const int lane = tid & 63;
    const int n15  = lane & 15;
    const int quad = lane >> 4;
    const int m0   = blockIdx.x * 64;
    const int j0   = blockIdx.y * 64;

    f32x4 acc[4];
    acc[0] = 0.f; acc[1] = 0.f; acc[2] = 0.f; acc[3] = 0.f;

    const int sj  = tid >> 2;
    const int skc = (tid & 3) * 8;
    const size_t xoff = (size_t)(m0 + wave * 16 + n15) * C_;

    for (int k0 = 0; k0 < C_; k0 += 32) {
        ushort8 wh, wl;
        #pragma unroll
        for (int i = 0; i < 8; ++i) {
            unsigned int p = split1(W[(size_t)(k0 + skc + i) * C_ + j0 + sj]);
            wh[i] = (unsigned short)p;
            wl[i] = (unsigned short)(p >> 16);
        }
        *(ushort8*)&WtH[sj][skc] = wh;
        *(ushort8*)&WtL[sj][skc] = wl;
        __syncthreads();

        bf16x8 Ah = ld_bf16x8(Xh + xoff + k0 + quad * 8);
        bf16x8 Al = ld_bf16x8(Xl + xoff + k0 + quad * 8);

        #pragma unroll
        for (int f = 0; f < 4; ++f) {
            bf16x8 Bh = ld_bf16x8(&WtH[f * 16 + n15][quad * 8]);
            bf16x8 Bl = ld_bf16x8(&WtL[f * 16 + n15][quad * 8]);
            acc[f] = __builtin_amdgcn_mfma_f32_16x16x32_bf16(Al, Bl, acc[f], 0, 0, 0);
            acc[f] = __builtin_amdgcn_mfma_f32_16x16x32_bf16(Al, Bh, acc[f], 0, 0, 0);
            acc[f] = __builtin_amdgcn_mfma_f32_16x16x32_bf16(Ah, Bl, acc[f], 0, 0, 0);
            acc[f] = __builtin_amdgcn_mfma_f32_16x16x32_bf16(Ah, Bh, acc[f], 0, 0, 0);
        }
        __syncthreads();
    }

    #pragma unroll
    for (int f = 0; f < 4; ++f) {
        const int j = j0 + f * 16 + n15;
        const float bj = bias[j];
        #pragma unroll
        for (int r = 0; r < 4; ++r) {
            const int grow = m0 + wave * 16 + quad * 4 + r;
            out[(size_t)grow * C_ + j] = acc[f][r] + bj;
        }
    }
}

// ---------------------------------------------------------------------------
// Fused flash attention, split-bf16 precision, mean-centered sim bias + mask.
// grid 256 = B * (Nq/16); block 512 = 8 waves, wave w == head w.
// mask is INT32 (harness uploads bool as int32: "integer -> const int*").
// ---------------------------------------------------------------------------
__global__ __launch_bounds__(512) void attn_kernel(const unsigned short* __restrict__ qh,
                                                   const unsigned short* __restrict__ ql,
                                                   const unsigned short* __restrict__ kh,
                                                   const unsigned short* __restrict__ kl,
                                                   const unsigned short* __restrict__ vh,
                                                   const unsigned short* __restrict__ vl,
                                                   const float* __restrict__ sim,
                                                   const int* __restrict__ mask,
                                                   unsigned short* __restrict__ xh,
                                                   unsigned short* __restrict__ xl)
{
    __shared__ float simLds[2][H_][16][32];      // 32 KB, layout fixed by global_load_lds
    __shared__ float biasLds[16][33];            // -mean (or -1e30 masked), padded
    __shared__ float pLds[H_][16 * 32];          // per-wave P round-trip, 16 KB

    const int tid  = threadIdx.x;
    const int wave = tid >> 6;    // head
    const int lane = tid & 63;
    const int n15  = lane & 15;
    const int quad = lane >> 4;
    const int wg   = blockIdx.x;
    const int b    = wg >> 7;
    const int q0   = (wg & 127) * 16;

    const size_t bh   = (size_t)(b * H_ + wave);
    const size_t qoff = (bh * NQ + q0 + n15) * HD + quad * 8;
    const unsigned short* khb = kh + bh * NK * HD;
    const unsigned short* klb = kl + bh * NK * HD;
    const unsigned short* vhb = vh + bh * HD * NK;
    const unsigned short* vlb = vl + bh * HD * NK;
    const float* gsim = sim + (bh * NQ + q0) * (size_t)NK
                            + (size_t)(lane >> 3) * NK + (lane & 7) * 4;

    const bf16x8 Qh = ld_bf16x8(qh + qoff);
    const bf16x8 Ql = ld_bf16x8(ql + qoff);

    f32x4 O0 = 0.f, O1 = 0.f;
    float m_r[4] = {0.f, 0.f, 0.f, 0.f};   // m-floor 0 (scores << 88, safe)
    float l_r[4] = {0.f, 0.f, 0.f, 0.f};

    async16(gsim,                  &simLds[0][wave][0][0]);
    async16(gsim + (size_t)8 * NK, &simLds[0][wave][8][0]);

    const float scale = 0.17677669529663687f;  // 1/sqrt(32)

    for (int it = 0; it < NK / 32; ++it) {
        const int k0  = it * 32;
        const int cur = it & 1;

        __syncthreads();  // B1: vmcnt drained before barrier -> tile `it` resident

        {   // mean-over-heads + mask -> biasLds (one element per thread)
            const int qq = tid >> 5, kk = tid & 31;
            float s = 0.f;
            #pragma unroll
            for (int h = 0; h < H_; ++h) s += simLds[cur][h][qq][kk];
            const int mk = mask[(size_t)(q0 + qq) * NK + k0 + kk];
            biasLds[qq][kk] = mk ? (-0.125f * s) : -1e30f;
        }
        __syncthreads();  // B2: bias visible

        if (it + 1 < NK / 32) {  // prefetch next sim tile (overlaps compute)
            const float* g = gsim + k0 + 32;
            async16(g,                  &simLds[cur ^ 1][wave][0][0]);
            async16(g + (size_t)8 * NK, &simLds[cur ^ 1][wave][8][0]);
        }

        // K frags: K[key = n15 / 16+n15][k = quad*8+j]
        const size_t koA = (size_t)(k0 + n15) * HD + quad * 8;
        const size_t koB = (size_t)(k0 + 16 + n15) * HD + quad * 8;
        bf16x8 Kh0 = ld_bf16x8(khb + koA), Kl0 = ld_bf16x8(klb + koA);
        bf16x8 Kh1 = ld_bf16x8(khb + koB), Kl1 = ld_bf16x8(klb + koB);

        f32x4 S0 = 0.f, S1 = 0.f;
        S0 = __builtin_amdgcn_mfma_f32_16x16x32_bf16(Ql, Kl0, S0, 0, 0, 0);
        S0 = __builtin_amdgcn_mfma_f32_16x16x32_bf16(Ql, Kh0, S0, 0, 0, 0);
        S0 = __builtin_amdgcn_mfma_f32_16x16x32_bf16(Qh, Kl0, S0, 0, 0, 0);
        S0 = __builtin_amdgcn_mfma_f32_16x16x32_bf16(Qh, Kh0, S0, 0, 0, 0);
        S1 = __builtin_amdgcn_mfma_f32_16x16x32_bf16(Ql, Kl1, S1, 0, 0, 0);
        S1 = __builtin_amdgcn_mfma_f32_16x16x32_bf16(Ql, Kh1, S1, 0, 0, 0);
        S1 = __builtin_amdgcn_mfma_f32_16x16x32_bf16(Qh, Kl1, S1, 0, 0, 0);
        S1 = __builtin_amdgcn_mfma_f32_16x16x32_bf16(Qh, Kh1, S1, 0, 0, 0);

        // V frags from V^T: V[k = key = quad*8+j][n = d = n15 / 16+n15]
        const size_t voA = (size_t)n15 * NK + k0 + quad * 8;
        const size_t voB = (size_t)(16 + n15) * NK + k0 + quad * 8;
        bf16x8 Vh0 = ld_bf16x8(vhb + voA), Vl0 = ld_bf16x8(vlb + voA);
        bf16x8 Vh1 = ld_bf16x8(vhb + voB), Vl1 = ld_bf16x8(vlb + voB);

        float P0[4], P1[4];
        #pragma unroll
        for (int r = 0; r < 4; ++r) {
            const int qq = quad * 4 + r;
            float s0 = S0[r] * scale + simLds[cur][wave][qq][n15]      + biasLds[qq][n15];
            float s1 = S1[r] * scale + simLds[cur][wave][qq][16 + n15] + biasLds[qq][16 + n15];

            float mx = fmaxf(s0, s1);
            #pragma unroll
            for (int off = 1; off < 16; off <<= 1) mx = fmaxf(mx, __shfl_xor(mx, off));
            const float mnew = fmaxf(m_r[r], mx);
            const float a  = __expf(m_r[r] - mnew);
            const float p0 = __expf(s0 - mnew);
            const float p1 = __expf(s1 - mnew);
            float sm = p0 + p1;
            #pragma unroll
            for (int off = 1; off < 16; off <<= 1) sm += __shfl_xor(sm, off);
            l_r[r] = l_r[r] * a + sm;
            m_r[r] = mnew;
            O0[r] *= a; O1[r] *= a;
            P0[r] = p0; P1[r] = p1;
        }

        // P (C-layout) -> per-wave LDS (f32) -> A-frag, split hi/lo
        float* pw = pLds[wave];
        #pragma unroll
        for (int r = 0; r < 4; ++r) {
            pw[(quad * 4 + r) * 32 + n15]      = P0[r];
            pw[(quad * 4 + r) * 32 + 16 + n15] = P1[r];
        }
        f32x4 pa = *(const f32x4*)(pw + n15 * 32 + quad * 8);
        f32x4 pb = *(const f32x4*)(pw + n15 * 32 + quad * 8 + 4);
        ushort8 phs, pls;
        #pragma unroll
        for (int i = 0; i < 4; ++i) {
            unsigned int pp0 = split1(pa[i]);
            unsigned int pp1 = split1(pb[i]);
            phs[i]     = (unsigned short)pp0;  pls[i]     = (unsigned short)(pp0 >> 16);
            phs[i + 4] = (unsigned short)pp1;  pls[i + 4] = (unsigned short)(pp1 >> 16);
        }
        bf16x8 Ph = __builtin_bit_cast(bf16x8, phs);
        bf16x8 Pl = __builtin_bit_cast(bf16x8, pls);

        O0 = __builtin_amdgcn_mfma_f32_16x16x32_bf16(Pl, Vl0, O0, 0, 0, 0);
        O0 = __builtin_amdgcn_mfma_f32_16x16x32_bf16(Pl, Vh0, O0, 0, 0, 0);
        O0 = __builtin_amdgcn_mfma_f32_16x16x32_bf16(Ph, Vl0, O0, 0, 0, 0);
        O0 = __builtin_amdgcn_mfma_f32_16x16x32_bf16(Ph, Vh0, O0, 0, 0, 0);
        O1 = __builtin_amdgcn_mfma_f32_16x16x32_bf16(Pl, Vl1, O1, 0, 0, 0);
        O1 = __builtin_amdgcn_mfma_f32_16x16x32_bf16(Pl, Vh1, O1, 0, 0, 0);
        O1 = __builtin_amdgcn_mfma_f32_16x16x32_bf16(Ph, Vl1, O1, 0, 0, 0);
        O1 = __builtin_amdgcn_mfma_f32_16x16x32_bf16(Ph, Vh1, O1, 0, 0, 0);
    }

    // epilogue: x[q][wave*32+d] = O/l, stored as split bf16 pair
    #pragma unroll
    for (int r = 0; r < 4; ++r) {
        const int q = q0 + quad * 4 + r;
        const float inv = 1.0f / l_r[r];
        const size_t base = (size_t)(b * NQ + q) * C_ + wave * HD;
        unsigned int p0 = split1(O0[r] * inv);
        unsigned int p1 = split1(O1[r] * inv);
        xh[base + n15]      = (unsigned short)p0;
        xl[base + n15]      = (unsigned short)(p0 >> 16);
        xh[base + 16 + n15] = (unsigned short)p1;
        xl[base + 16 + n15] = (unsigned short)(p1 >> 16);
    }
}

extern "C" void kernel_launch(void* const* d_in, const int* in_sizes, int n_in,
                              void* d_out, int out_size, void* d_ws, size_t ws_size,
                              hipStream_t stream) {
    const float* query = (const float*)d_in[0];
    const float* key   = (const float*)d_in[1];
    const float* value = (const float*)d_in[2];
    // d_in[3] qpos, d_in[4] kpos: unused (rope is None)
    const int*   mask  = (const int*)d_in[5];   // bool uploaded as int32 per harness
    const float* sim   = (const float*)d_in[6];
    const float* Wq  = (const float*)d_in[7];
    const float* Wk  = (const float*)d_in[8];
    const float* Wv  = (const float*)d_in[9];
    const float* Wp  = (const float*)d_in[10];
    const float* bp  = (const float*)d_in[11];
    float* out = (float*)d_out;

    // workspace: 8 bf16 arrays of B*H*N*HD = 1,048,576 elements (2 MB) each = 16 MB
    const size_t NEL = (size_t)B_ * H_ * NQ * HD;
    unsigned short* qbh = (unsigned short*)d_ws;
    unsigned short* qbl = qbh + NEL;
    unsigned short* kbh = qbl + NEL;
    unsigned short* kbl = kbh + NEL;
    unsigned short* vbh = kbl + NEL;
    unsigned short* vbl = vbh + NEL;
    unsigned short* xbh = vbl + NEL;
    unsigned short* xbl = xbh + NEL;

    dim3 g(64, 4, 1);
    proj_kernel<<<g, 256, 0, stream>>>(query, Wq, qbh, qbl, 0);
    proj_kernel<<<g, 256, 0, stream>>>(key,   Wk, kbh, kbl, 0);
    proj_kernel<<<g, 256, 0, stream>>>(value, Wv, vbh, vbl, 1);
    attn_kernel<<<256, 512, 0, stream>>>(qbh, qbl, kbh, kbl, vbh, vbl, sim, mask, xbh, xbl);
    outproj_kernel<<<g, 256, 0, stream>>>(xbh, xbl, Wp, bp, out);
}

// Round 5
// 568.479 us; speedup vs baseline: 1.0742x; 1.0742x over previous
//
#include <hip/hip_runtime.h>

#define B_  2
#define NQ  2048
#define NK  2048
#define C_  256
#define H_  8
#define HD  32
#define SPLIT 4
#define KSEG (NK / SPLIT)          // 512 keys per WG
#define KT   (KSEG / 32)           // 16 tiles of 32 keys
#define QT_  (NQ / 16)             // 128 q-tiles
#define PART_STRIDE 544            // 512 O + 16 m + 16 l (f32)

typedef float f32x4 __attribute__((ext_vector_type(4)));
typedef __bf16 bf16x8 __attribute__((ext_vector_type(8)));
typedef unsigned short ushort8 __attribute__((ext_vector_type(8)));

// f32 -> bf16 round-to-nearest-even
static __device__ __forceinline__ unsigned short f2bf(float f) {
    unsigned int u = __builtin_bit_cast(unsigned int, f);
    u += 0x7FFFu + ((u >> 16) & 1u);
    return (unsigned short)(u >> 16);
}
static __device__ __forceinline__ float bf2f(unsigned short h) {
    unsigned int u = ((unsigned int)h) << 16;
    return __builtin_bit_cast(float, u);
}
// split f32 -> (hi bf16 in low 16, lo bf16 in high 16); hi+lo ~ f to 2^-19 rel
static __device__ __forceinline__ unsigned int split1(float f) {
    unsigned short h = f2bf(f);
    unsigned short l = f2bf(f - bf2f(h));
    return (unsigned int)h | ((unsigned int)l << 16);
}
static __device__ __forceinline__ bf16x8 ld_bf16x8(const unsigned short* p) {
    return __builtin_bit_cast(bf16x8, *(const ushort8*)p);
}
// async global->LDS, 16B per lane; LDS dest = wave-uniform base + lane*16
static __device__ __forceinline__ void async16(const void* g, void* l) {
    __builtin_amdgcn_global_load_lds((__attribute__((address_space(1))) void*)g,
                                     (__attribute__((address_space(3))) void*)l,
                                     16, 0, 0);
}

// ---------------------------------------------------------------------------
// Fused Q/K/V projection GEMM (split-bf16 4-term MFMA), selected by blockIdx.z.
// z=0: Q (row layout)  z=1: K (row layout)  z=2: V (transposed layout)
// grid (64,4,3), block 256 (4 waves); tile 64x64, K-step 32.
// ---------------------------------------------------------------------------
__global__ __launch_bounds__(256) void proj_kernel(
        const float* __restrict__ query, const float* __restrict__ key,
        const float* __restrict__ value,
        const float* __restrict__ Wq, const float* __restrict__ Wk,
        const float* __restrict__ Wv,
        unsigned short* __restrict__ qbh, unsigned short* __restrict__ qbl,
        unsigned short* __restrict__ kbh, unsigned short* __restrict__ kbl,
        unsigned short* __restrict__ vbh, unsigned short* __restrict__ vbl)
{
    __shared__ unsigned short WtH[64][32];
    __shared__ unsigned short WtL[64][32];

    const int z = blockIdx.z;
    const float* X = (z == 0) ? query : (z == 1) ? key : value;
    const float* W = (z == 0) ? Wq    : (z == 1) ? Wk  : Wv;
    unsigned short* dh = (z == 0) ? qbh : (z == 1) ? kbh : vbh;
    unsigned short* dl = (z == 0) ? qbl : (z == 1) ? kbl : vbl;
    const int vmode = (z == 2);

    const int tid  = threadIdx.x;
    const int wave = tid >> 6;
    const int lane = tid & 63;
    const int n15  = lane & 15;
    const int quad = lane >> 4;
    const int m0   = blockIdx.x * 64;
    const int j0   = blockIdx.y * 64;

    f32x4 acc[4];
    acc[0] = 0.f; acc[1] = 0.f; acc[2] = 0.f; acc[3] = 0.f;

    const int sj  = tid >> 2;
    const int skc = (tid & 3) * 8;
    const float* __restrict__ xrow = X + (size_t)(m0 + wave * 16 + n15) * C_;

    for (int k0 = 0; k0 < C_; k0 += 32) {
        ushort8 wh, wl;
        #pragma unroll
        for (int i = 0; i < 8; ++i) {
            unsigned int p = split1(W[(size_t)(k0 + skc + i) * C_ + j0 + sj]);
            wh[i] = (unsigned short)p;
            wl[i] = (unsigned short)(p >> 16);
        }
        *(ushort8*)&WtH[sj][skc] = wh;
        *(ushort8*)&WtL[sj][skc] = wl;
        __syncthreads();

        f32x4 a0 = *(const f32x4*)(xrow + k0 + quad * 8);
        f32x4 a1 = *(const f32x4*)(xrow + k0 + quad * 8 + 4);
        ushort8 ah, al;
        #pragma unroll
        for (int i = 0; i < 4; ++i) {
            unsigned int p0 = split1(a0[i]);
            unsigned int p1 = split1(a1[i]);
            ah[i]     = (unsigned short)p0;  al[i]     = (unsigned short)(p0 >> 16);
            ah[i + 4] = (unsigned short)p1;  al[i + 4] = (unsigned short)(p1 >> 16);
        }
        bf16x8 Ah = __builtin_bit_cast(bf16x8, ah);
        bf16x8 Al = __builtin_bit_cast(bf16x8, al);

        #pragma unroll
        for (int f = 0; f < 4; ++f) {
            bf16x8 Bh = ld_bf16x8(&WtH[f * 16 + n15][quad * 8]);
            bf16x8 Bl = ld_bf16x8(&WtL[f * 16 + n15][quad * 8]);
            acc[f] = __builtin_amdgcn_mfma_f32_16x16x32_bf16(Al, Bl, acc[f], 0, 0, 0);
            acc[f] = __builtin_amdgcn_mfma_f32_16x16x32_bf16(Al, Bh, acc[f], 0, 0, 0);
            acc[f] = __builtin_amdgcn_mfma_f32_16x16x32_bf16(Ah, Bl, acc[f], 0, 0, 0);
            acc[f] = __builtin_amdgcn_mfma_f32_16x16x32_bf16(Ah, Bh, acc[f], 0, 0, 0);
        }
        __syncthreads();
    }

    #pragma unroll
    for (int f = 0; f < 4; ++f) {
        const int j = j0 + f * 16 + n15;
        const int h = j >> 5, dd = j & 31;
        #pragma unroll
        for (int r = 0; r < 4; ++r) {
            const int grow = m0 + wave * 16 + quad * 4 + r;
            const int b = grow >> 11, row = grow & 2047;
            unsigned int p = split1(acc[f][r]);
            size_t idx;
            if (vmode) idx = (size_t)((b * H_ + h) * HD + dd) * NK + row;
            else       idx = (size_t)((b * H_ + h) * NK + row) * HD + dd;
            dh[idx] = (unsigned short)p;
            dl[idx] = (unsigned short)(p >> 16);
        }
    }
}

// ---------------------------------------------------------------------------
// Output projection: out[m,j] = sum_k x[m,k]*Wp[k,j] + bp[j], f32 out.
// ---------------------------------------------------------------------------
__global__ __launch_bounds__(256) void outproj_kernel(const unsigned short* __restrict__ Xh,
                                                      const unsigned short* __restrict__ Xl,
                                                      const float* __restrict__ W,
                                                      const float* __restrict__ bias,
                                                      float* __restrict__ out)
{
    __shared__ unsigned short WtH[64][32];
    __shared__ unsigned short WtL[64][32];

    const int tid  = threadIdx.x;
    const int wave = tid >> 6;
    const int lane = tid & 63;
    const int n15  = lane & 15;
    const int quad = lane >> 4;
    const int m0   = blockIdx.x * 64;
    const int j0   = blockIdx.y * 64;

    f32x4 acc[4];
    acc[0] = 0.f; acc[1] = 0.f; acc[2] = 0.f; acc[3] = 0.f;

    const int sj  = tid >> 2;
    const int skc = (tid & 3) * 8;
    const size_t xoff = (size_t)(m0 + wave * 16 + n15) * C_;

    for (int k0 = 0; k0 < C_; k0 += 32) {
        ushort8 wh, wl;
        #pragma unroll
        for (int i = 0; i < 8; ++i) {
            unsigned int p = split1(W[(size_t)(k0 + skc + i) * C_ + j0 + sj]);
            wh[i] = (unsigned short)p;
            wl[i] = (unsigned short)(p >> 16);
        }
        *(ushort8*)&WtH[sj][skc] = wh;
        *(ushort8*)&WtL[sj][skc] = wl;
        __syncthreads();

        bf16x8 Ah = ld_bf16x8(Xh + xoff + k0 + quad * 8);
        bf16x8 Al = ld_bf16x8(Xl + xoff + k0 + quad * 8);

        #pragma unroll
        for (int f = 0; f < 4; ++f) {
            bf16x8 Bh = ld_bf16x8(&WtH[f * 16 + n15][quad * 8]);
            bf16x8 Bl = ld_bf16x8(&WtL[f * 16 + n15][quad * 8]);
            acc[f] = __builtin_amdgcn_mfma_f32_16x16x32_bf16(Al, Bl, acc[f], 0, 0, 0);
            acc[f] = __builtin_amdgcn_mfma_f32_16x16x32_bf16(Al, Bh, acc[f], 0, 0, 0);
            acc[f] = __builtin_amdgcn_mfma_f32_16x16x32_bf16(Ah, Bl, acc[f], 0, 0, 0);
            acc[f] = __builtin_amdgcn_mfma_f32_16x16x32_bf16(Ah, Bh, acc[f], 0, 0, 0);
        }
        __syncthreads();
    }

    #pragma unroll
    for (int f = 0; f < 4; ++f) {
        const int j = j0 + f * 16 + n15;
        const float bj = bias[j];
        #pragma unroll
        for (int r = 0; r < 4; ++r) {
            const int grow = m0 + wave * 16 + quad * 4 + r;
            out[(size_t)grow * C_ + j] = acc[f][r] + bj;
        }
    }
}

// ---------------------------------------------------------------------------
// Flash attention, split-K x4. grid 1024 = SPLIT * B * (Nq/16); block 512.
// Wave w == head w. Writes unnormalized partial (O, m, l) per (s,b,h,qt).
// LDS = 48.1 KB -> 3 WGs/CU. Mask prefetched via global_load_lds (no
// dependent global load between barriers).
// ---------------------------------------------------------------------------
__global__ __launch_bounds__(512, 6) void attn_kernel(
        const unsigned short* __restrict__ qh, const unsigned short* __restrict__ ql,
        const unsigned short* __restrict__ kh, const unsigned short* __restrict__ kl,
        const unsigned short* __restrict__ vh, const unsigned short* __restrict__ vl,
        const float* __restrict__ sim, const int* __restrict__ mask,
        float* __restrict__ part)
{
    __shared__ float simLds[2][H_][16][32];                 // 32 KB (async16 layout)
    __shared__ int   maskLds[2][16][32];                    // 4 KB  (async16 layout)
    __shared__ float biasLds[16][33];                       // 2.1 KB
    __shared__ __align__(16) unsigned short pLds[H_][16 * 40]; // 10 KB, two-pass hi/lo

    const int tid  = threadIdx.x;
    const int wave = tid >> 6;    // head
    const int lane = tid & 63;
    const int n15  = lane & 15;
    const int quad = lane >> 4;

    const int wg   = blockIdx.x;
    const int s    = wg >> 8;          // key split 0..3
    const int rem  = wg & 255;
    const int b    = rem >> 7;
    const int qt   = rem & 127;
    const int q0   = qt * 16;
    const int kbeg = s * KSEG;

    const size_t bh   = (size_t)(b * H_ + wave);
    const size_t qoff = (bh * NQ + q0 + n15) * HD + quad * 8;
    const unsigned short* khb = kh + bh * NK * HD;
    const unsigned short* klb = kl + bh * NK * HD;
    const unsigned short* vhb = vh + bh * HD * NK;
    const unsigned short* vlb = vl + bh * HD * NK;
    // per-lane async16 src: row = lane>>3 (8 rows/call), 4 f32 at (lane&7)*4
    const float* gsim = sim + (bh * NQ + q0) * (size_t)NK + kbeg
                            + (size_t)(lane >> 3) * NK + (lane & 7) * 4;
    const int* gmask = mask + (size_t)(q0 + (lane >> 3)) * NK + kbeg + (lane & 7) * 4;

    const bf16x8 Qh = ld_bf16x8(qh + qoff);
    const bf16x8 Ql = ld_bf16x8(ql + qoff);

    f32x4 O0 = 0.f, O1 = 0.f;
    float m_r[4] = {0.f, 0.f, 0.f, 0.f};   // m-floor 0 (scores << 88, safe)
    float l_r[4] = {0.f, 0.f, 0.f, 0.f};

    // prologue: prefetch tile 0 (sim per-head, mask by wave 0)
    async16(gsim,                  &simLds[0][wave][0][0]);
    async16(gsim + (size_t)8 * NK, &simLds[0][wave][8][0]);
    if (wave == 0) {
        async16(gmask,                  &maskLds[0][0][0]);
        async16(gmask + (size_t)8 * NK, &maskLds[0][8][0]);
    }

    const float scale = 0.17677669529663687f;  // 1/sqrt(32)

    for (int it = 0; it < KT; ++it) {
        const int k0  = kbeg + it * 32;   // absolute key base
        const int cur = it & 1;

        __syncthreads();  // B1: vmcnt drained -> sim+mask tile `it` resident

        {   // mean-over-heads + mask -> biasLds (one element per thread)
            const int qq = tid >> 5, kk = tid & 31;
            float sum = 0.f;
            #pragma unroll
            for (int h = 0; h < H_; ++h) sum += simLds[cur][h][qq][kk];
            biasLds[qq][kk] = maskLds[cur][qq][kk] ? (-0.125f * sum) : -1e30f;
        }
        __syncthreads();  // B2: bias visible

        if (it + 1 < KT) {  // prefetch next tile (overlaps compute below)
            const float* g  = gsim + it * 32 + 32;
            async16(g,                  &simLds[cur ^ 1][wave][0][0]);
            async16(g + (size_t)8 * NK, &simLds[cur ^ 1][wave][8][0]);
            if (wave == 0) {
                const int* gm = gmask + it * 32 + 32;
                async16(gm,                  &maskLds[cur ^ 1][0][0]);
                async16(gm + (size_t)8 * NK, &maskLds[cur ^ 1][8][0]);
            }
        }

        // K frags: K[key = k0+n15 / k0+16+n15][k = quad*8+j]
        const size_t koA = (size_t)(k0 + n15) * HD + quad * 8;
        const size_t koB = (size_t)(k0 + 16 + n15) * HD + quad * 8;
        bf16x8 Kh0 = ld_bf16x8(khb + koA), Kl0 = ld_bf16x8(klb + koA);
        bf16x8 Kh1 = ld_bf16x8(khb + koB), Kl1 = ld_bf16x8(klb + koB);

        f32x4 S0 = 0.f, S1 = 0.f;
        S0 = __builtin_amdgcn_mfma_f32_16x16x32_bf16(Ql, Kl0, S0, 0, 0, 0);
        S0 = __builtin_amdgcn_mfma_f32_16x16x32_bf16(Ql, Kh0, S0, 0, 0, 0);
        S0 = __builtin_amdgcn_mfma_f32_16x16x32_bf16(Qh, Kl0, S0, 0, 0, 0);
        S0 = __builtin_amdgcn_mfma_f32_16x16x32_bf16(Qh, Kh0, S0, 0, 0, 0);
        S1 = __builtin_amdgcn_mfma_f32_16x16x32_bf16(Ql, Kl1, S1, 0, 0, 0);
        S1 = __builtin_amdgcn_mfma_f32_16x16x32_bf16(Ql, Kh1, S1, 0, 0, 0);
        S1 = __builtin_amdgcn_mfma_f32_16x16x32_bf16(Qh, Kl1, S1, 0, 0, 0);
        S1 = __builtin_amdgcn_mfma_f32_16x16x32_bf16(Qh, Kh1, S1, 0, 0, 0);

        // V frags from V^T: V[k = key = k0+quad*8+j][n = d = n15 / 16+n15]
        const size_t voA = (size_t)n15 * NK + k0 + quad * 8;
        const size_t voB = (size_t)(16 + n15) * NK + k0 + quad * 8;
        bf16x8 Vh0 = ld_bf16x8(vhb + voA), Vl0 = ld_bf16x8(vlb + voA);
        bf16x8 Vh1 = ld_bf16x8(vhb + voB), Vl1 = ld_bf16x8(vlb + voB);

        unsigned int u0[4], u1[4];
        #pragma unroll
        for (int r = 0; r < 4; ++r) {
            const int qq = quad * 4 + r;
            float s0 = S0[r] * scale + simLds[cur][wave][qq][n15]      + biasLds[qq][n15];
            float s1 = S1[r] * scale + simLds[cur][wave][qq][16 + n15] + biasLds[qq][16 + n15];

            float mx = fmaxf(s0, s1);
            #pragma unroll
            for (int off = 1; off < 16; off <<= 1) mx = fmaxf(mx, __shfl_xor(mx, off));
            const float mnew = fmaxf(m_r[r], mx);
            const float a  = __expf(m_r[r] - mnew);
            const float p0 = __expf(s0 - mnew);
            const float p1 = __expf(s1 - mnew);
            float sm = p0 + p1;
            #pragma unroll
            for (int off = 1; off < 16; off <<= 1) sm += __shfl_xor(sm, off);
            l_r[r] = l_r[r] * a + sm;
            m_r[r] = mnew;
            O0[r] *= a; O1[r] *= a;
            u0[r] = split1(p0); u1[r] = split1(p1);
        }

        // P (C-layout) -> per-wave LDS -> A-frag; two passes (hi, then lo)
        // through one bf16 buffer (per-wave DS ops are in-order).
        unsigned short* pw = pLds[wave];
        #pragma unroll
        for (int r = 0; r < 4; ++r) {
            const int qq = quad * 4 + r;
            pw[qq * 40 + n15]      = (unsigned short)u0[r];
            pw[qq * 40 + 16 + n15] = (unsigned short)u1[r];
        }
        bf16x8 Ph = ld_bf16x8(pw + n15 * 40 + quad * 8);
        #pragma unroll
        for (int r = 0; r < 4; ++r) {
            const int qq = quad * 4 + r;
            pw[qq * 40 + n15]      = (unsigned short)(u0[r] >> 16);
            pw[qq * 40 + 16 + n15] = (unsigned short)(u1[r] >> 16);
        }
        bf16x8 Pl = ld_bf16x8(pw + n15 * 40 + quad * 8);

        O0 = __builtin_amdgcn_mfma_f32_16x16x32_bf16(Pl, Vl0, O0, 0, 0, 0);
        O0 = __builtin_amdgcn_mfma_f32_16x16x32_bf16(Pl, Vh0, O0, 0, 0, 0);
        O0 = __builtin_amdgcn_mfma_f32_16x16x32_bf16(Ph, Vl0, O0, 0, 0, 0);
        O0 = __builtin_amdgcn_mfma_f32_16x16x32_bf16(Ph, Vh0, O0, 0, 0, 0);
        O1 = __builtin_amdgcn_mfma_f32_16x16x32_bf16(Pl, Vl1, O1, 0, 0, 0);
        O1 = __builtin_amdgcn_mfma_f32_16x16x32_bf16(Pl, Vh1, O1, 0, 0, 0);
        O1 = __builtin_amdgcn_mfma_f32_16x16x32_bf16(Ph, Vl1, O1, 0, 0, 0);
        O1 = __builtin_amdgcn_mfma_f32_16x16x32_bf16(Ph, Vh1, O1, 0, 0, 0);
    }

    // epilogue: write unnormalized partial (O, m, l)
    float* pb = part + (size_t)(((s * B_ + b) * H_ + wave) * QT_ + qt) * PART_STRIDE;
    #pragma unroll
    for (int r = 0; r < 4; ++r) {
        const int q = quad * 4 + r;
        pb[q * 32 + n15]      = O0[r];
        pb[q * 32 + 16 + n15] = O1[r];
        if (n15 == 0) {
            pb[512 + q] = m_r[r];
            pb[528 + q] = l_r[r];
        }
    }
}

// ---------------------------------------------------------------------------
// Split-K combine: merge SPLIT partials per (b,h,qt), write split-bf16 x.
// One wave per (b,h,qt): 2048 waves -> grid 512 x 256.
// ---------------------------------------------------------------------------
__global__ __launch_bounds__(256) void combine_kernel(const float* __restrict__ part,
                                                      unsigned short* __restrict__ xh,
                                                      unsigned short* __restrict__ xl)
{
    const int wid  = blockIdx.x * 4 + (threadIdx.x >> 6);  // 0..2047
    const int lane = threadIdx.x & 63;
    const int b  = wid >> 10;
    const int h  = (wid >> 7) & 7;
    const int qt = wid & 127;
    const int q  = lane >> 2;
    const int d0 = (lane & 3) * 8;

    float ms[SPLIT], ls[SPLIT];
    float mstar = -1e30f;
    #pragma unroll
    for (int s = 0; s < SPLIT; ++s) {
        const float* pb = part + (size_t)(((s * B_ + b) * H_ + h) * QT_ + qt) * PART_STRIDE;
        ms[s] = pb[512 + q];
        ls[s] = pb[528 + q];
        mstar = fmaxf(mstar, ms[s]);
    }
    f32x4 acc0 = 0.f, acc1 = 0.f;
    float lsum = 0.f;
    #pragma unroll
    for (int s = 0; s < SPLIT; ++s) {
        const float* pb = part + (size_t)(((s * B_ + b) * H_ + h) * QT_ + qt) * PART_STRIDE;
        const float w = __expf(ms[s] - mstar);
        lsum += w * ls[s];
        f32x4 o0 = *(const f32x4*)(pb + q * 32 + d0);
        f32x4 o1 = *(const f32x4*)(pb + q * 32 + d0 + 4);
        acc0 += w * o0;
        acc1 += w * o1;
    }
    const float inv = 1.0f / lsum;
    const size_t base = (size_t)(b * NQ + qt * 16 + q) * C_ + h * HD + d0;
    #pragma unroll
    for (int i = 0; i < 4; ++i) {
        unsigned int p0 = split1(acc0[i] * inv);
        unsigned int p1 = split1(acc1[i] * inv);
        xh[base + i]     = (unsigned short)p0;
        xl[base + i]     = (unsigned short)(p0 >> 16);
        xh[base + 4 + i] = (unsigned short)p1;
        xl[base + 4 + i] = (unsigned short)(p1 >> 16);
    }
}

extern "C" void kernel_launch(void* const* d_in, const int* in_sizes, int n_in,
                              void* d_out, int out_size, void* d_ws, size_t ws_size,
                              hipStream_t stream) {
    const float* query = (const float*)d_in[0];
    const float* key   = (const float*)d_in[1];
    const float* value = (const float*)d_in[2];
    // d_in[3] qpos, d_in[4] kpos: unused (rope is None)
    const int*   mask  = (const int*)d_in[5];   // bool uploaded as int32
    const float* sim   = (const float*)d_in[6];
    const float* Wq  = (const float*)d_in[7];
    const float* Wk  = (const float*)d_in[8];
    const float* Wv  = (const float*)d_in[9];
    const float* Wp  = (const float*)d_in[10];
    const float* bp  = (const float*)d_in[11];
    float* out = (float*)d_out;

    // workspace: 8 x 2MB bf16 arrays (16 MB) + split-K partials (17.8 MB)
    const size_t NEL = (size_t)B_ * H_ * NQ * HD;   // 1,048,576
    unsigned short* qbh = (unsigned short*)d_ws;
    unsigned short* qbl = qbh + NEL;
    unsigned short* kbh = qbl + NEL;
    unsigned short* kbl = kbh + NEL;
    unsigned short* vbh = kbl + NEL;
    unsigned short* vbl = vbh + NEL;
    unsigned short* xbh = vbl + NEL;
    unsigned short* xbl = xbh + NEL;
    float* part = (float*)(xbl + NEL);  // SPLIT*B*H*QT*544 f32 = 17.8 MB

    proj_kernel<<<dim3(64, 4, 3), 256, 0, stream>>>(query, key, value, Wq, Wk, Wv,
                                                    qbh, qbl, kbh, kbl, vbh, vbl);
    attn_kernel<<<SPLIT * 256, 512, 0, stream>>>(qbh, qbl, kbh, kbl, vbh, vbl,
                                                 sim, mask, part);
    combine_kernel<<<512, 256, 0, stream>>>(part, xbh, xbl);
    outproj_kernel<<<dim3(64, 4), 256, 0, stream>>>(xbh, xbl, Wp, bp, out);
}